// Round 4
// baseline (702.466 us; speedup 1.0000x reference)
//
#include <hip/hip_runtime.h>
#include <hip/hip_fp16.h>
#include <stdint.h>

// SNNClassifier: B=16384, F=256, H=256, C=10, T=100
// Phase 1: layer-1 LIF spike bitmask into d_ws (100 x 16384 x 256 bits).
// Phase 2: persistent-state fused kernel: h = Z(t) @ W^T via f16 split-2
//          MFMA (W = Whi + 2^-11 * Wlo'), bit-exact-vs-numpy LIF, fused
//          readout epilogue.
//
// R4 changes (R3: snn_main 503us, VALUBusy 45%, MfmaUtil 37%, 436MB spill
// writes -> stall-dominated, 3x above the ~160us pipe floor):
//  1. Manual depth-1 SW pipeline on W-fragments: Bf[2][4] double buffer,
//     each k-region prefetches the NEXT region's 4 ds_read_b128 (wrapping
//     LO->HI->next-tg LO; W is t-stationary so steady state has no bubble).
//     One sched_barrier(0) per k caps hoisting (R1's spill cause).
//  2. Single WS[2][64][264] LDS array: every ds_read uses ONE vgpr address
//     + 16-bit imm offset (max 59584 < 65536) -> kills the 64-entry LDS
//     address CSE set that drove R3's 436MB of scratch spill.
//  3. zb loads for tg+1 issued before the LIF section (~1200 cyc cover),
//     in-place (no extra regs). Unpack trimmed 18->14 VALU (shared mul).
// Live set ~= acc64 + zb32 + state48 + Bf32 + misc ~= 200 < 256 @ 2 w/EU.

#define BB 16384
#define FF 256
#define HH 256
#define CC 10
#define TT 100

typedef __attribute__((ext_vector_type(8))) _Float16 half8;
typedef __attribute__((ext_vector_type(4))) float f32x4;

// ---------------- kernel 1: layer-1 spike bitmask ----------------
// Block = 256 thr = 4 waves; wave owns 4 b-values x 4 segs (16 LIF states
// per thread). Per t, lanes 0..15 store 16 u64 = 128B contiguous.
__global__ __launch_bounds__(256) void spike_gen(
    const float* __restrict__ x, unsigned long long* __restrict__ Z) {
  const int lane = threadIdx.x & 63;
  const int wv   = threadIdx.x >> 6;
  const int b0   = blockIdx.x * 16 + wv * 4;  // this wave's 4 b-values
  const float K_VM = (float)(0.001 * 100.0);        // 0.1f, numpy-exact
  const float K_ID = (float)(1.0 - 0.001 * 200.0);  // 0.8f, numpy-exact

  float v[16], cur[16], xv[16];
#pragma unroll
  for (int jb = 0; jb < 4; ++jb)
#pragma unroll
    for (int js = 0; js < 4; ++js) {
      const int idx = jb * 4 + js;
      xv[idx] = x[(size_t)(b0 + jb) * FF + js * 64 + lane];
      v[idx] = 0.0f; cur[idx] = 0.0f;
    }

  unsigned long long mymask = 0;
  unsigned long long* zp = Z + (size_t)b0 * 4;  // row slot base (u64 units)

  for (int t = 0; t < TT; ++t) {
#pragma unroll
    for (int idx = 0; idx < 16; ++idx) {
      float vd   = __fadd_rn(v[idx], __fmul_rn(K_VM, __fadd_rn(-v[idx], cur[idx])));
      float idec = __fmul_rn(cur[idx], K_ID);
      bool z = (vd > 1.0f);
      unsigned long long m = __ballot(z);
      if (lane == idx) mymask = m;  // lane idx owns slot (b0+jb)*4+js
      v[idx]   = z ? 0.0f : vd;
      cur[idx] = __fadd_rn(idec, xv[idx]);
    }
    if (lane < 16) zp[(size_t)t * (BB * 4) + lane] = mymask;
  }
}

// unpack 8 spike bits -> 8 f16 values (0.0/1.0) in MFMA A-fragment order.
// byte must be pre-masked to 8 bits. t = byte|byte<<15 puts bit(2p) at
// bit(2p) and bit(2p+1) at bit(2p+16); &0x10001 then *0x3C00 -> f16 pair.
__device__ __forceinline__ half8 unpack_byte_f16(uint32_t byte) {
  union { uint32_t u[4]; half8 h; } r;
  const uint32_t t = byte * 0x8001u;
#pragma unroll
  for (int p = 0; p < 4; ++p)
    r.u[p] = ((t >> (2 * p)) & 0x10001u) * 0x3C00u;
  return r.h;
}

// ---------------- kernel 2: fused temporal loop ----------------
// grid: (B/64) b-chunks x 4 h-chunks. block=256 (4 waves).
// wave tile: 16 b-rows x 64 h-cols, 4 timestep-planes per group.
__global__ __launch_bounds__(256, 2) void snn_main(
    const uint32_t* __restrict__ Z, const float* __restrict__ Wh,
    const float* __restrict__ bh, const float* __restrict__ Wr,
    const float* __restrict__ br, float* __restrict__ out) {
  // WS[0] = hi digit, WS[1] = lo digit (x2048). One array so all reads
  // share one base address + immediate offsets. Row pad 264 (+16B).
  __shared__ __align__(16) _Float16 WS[2][64][264];

  const int tid = threadIdx.x;
  const int bx  = blockIdx.x;
  const int hc  = bx & 3;
  const int bc  = bx >> 2;
  const int h0  = hc * 64;
  const int b0  = bc * 64;

  // ---- stage W -> LDS as (hi, lo*2048) f16 digits, denormal-guarded ----
  {
    const int r  = tid >> 2;         // 0..63 row
    const int f0 = (tid & 3) * 64;   // f segment
    const float* wrow = Wh + (size_t)(h0 + r) * FF + f0;
#pragma unroll 8
    for (int j = 0; j < 64; ++j) {
      float w = wrow[j];
      _Float16 hi = (fabsf(w) < 6.2e-5f) ? (_Float16)0.0f : (_Float16)w;
      _Float16 lo = (_Float16)((w - (float)hi) * 2048.0f);
      WS[0][r][f0 + j] = hi;
      WS[1][r][f0 + j] = lo;
    }
  }
  __syncthreads();

  const int lane = tid & 63;
  const int wv   = tid >> 6;       // wave 0..3 -> b sub-tile
  const int col  = lane & 15;      // A: m-row / B: n-col / C: col
  const int quad = lane >> 4;      // k-chunk selector
  const int q8   = quad * 8;

  const int brow = b0 + wv * 16 + col;  // A-operand b row for this lane

  // single runtime LDS base; everything else is a 16-bit imm offset
  const char* wsb = (const char*)&WS[0][0][0] + (size_t)((col * 264 + q8) * 2);
#define WREAD(d, nt, k) \
  (*(const half8*)(wsb + ((d) * 33792 + (nt) * 8448 + (k) * 64)))

  const float K_VM = (float)(0.001 * 100.0);
  const float K_ID = (float)(1.0 - 0.001 * 200.0);

  float v2[4][4], ii[4][4], sc[4][4];
#pragma unroll
  for (int nt = 0; nt < 4; ++nt)
#pragma unroll
    for (int r = 0; r < 4; ++r) { v2[nt][r] = 0.f; ii[nt][r] = 0.f; sc[nt][r] = 0.f; }

  float bias[4];
#pragma unroll
  for (int nt = 0; nt < 4; ++nt) bias[nt] = bh[h0 + nt * 16 + col];

  // zb for tg=0; subsequent tg's loads issue before the LIF section
  uint32_t zb[4][8];
  const uint32_t* zrow = Z + (size_t)brow * 8;
#pragma unroll
  for (int j = 0; j < 4; ++j) {
    const uint32_t* p = zrow + (size_t)j * (BB * 8);
    uint4 a = *(const uint4*)p;
    uint4 bq = *(const uint4*)(p + 4);
    zb[j][0] = a.x; zb[j][1] = a.y; zb[j][2] = a.z; zb[j][3] = a.w;
    zb[j][4] = bq.x; zb[j][5] = bq.y; zb[j][6] = bq.z; zb[j][7] = bq.w;
  }

  // pipeline prologue: LO k=0 fragments into buffer 0
  half8 Bf[2][4];
#pragma unroll
  for (int nt = 0; nt < 4; ++nt) Bf[0][nt] = WREAD(1, nt, 0);

#pragma unroll 1
  for (int tg = 0; tg < TT / 4; ++tg) {
    f32x4 acc[4][4];
#pragma unroll
    for (int j = 0; j < 4; ++j)
#pragma unroll
      for (int nt = 0; nt < 4; ++nt)
        acc[j][nt] = (f32x4){0.f, 0.f, 0.f, 0.f};

    // ---- phase LO: acc = Z . Wlo' ---- (prefetch next region's Bf)
#pragma unroll
    for (int k = 0; k < 8; ++k) {
      const int cb = k & 1, nb = cb ^ 1;
      if (k < 7) {
#pragma unroll
        for (int nt = 0; nt < 4; ++nt) Bf[nb][nt] = WREAD(1, nt, k + 1);
      } else {
#pragma unroll
        for (int nt = 0; nt < 4; ++nt) Bf[nb][nt] = WREAD(0, nt, 0);
      }
#pragma unroll
      for (int j = 0; j < 4; ++j) {
        half8 Af = unpack_byte_f16((zb[j][k] >> q8) & 0xFFu);
#pragma unroll
        for (int nt = 0; nt < 4; ++nt)
          acc[j][nt] = __builtin_amdgcn_mfma_f32_16x16x32_f16(
              Af, Bf[cb][nt], acc[j][nt], 0, 0, 0);
      }
      __builtin_amdgcn_sched_barrier(0);
    }

    // exact power-of-2 rescale of lo digit
#pragma unroll
    for (int j = 0; j < 4; ++j)
#pragma unroll
      for (int nt = 0; nt < 4; ++nt)
#pragma unroll
        for (int r = 0; r < 4; ++r)
          acc[j][nt][r] = __fmul_rn(acc[j][nt][r], 4.8828125e-4f); // 2^-11

    // ---- phase HI: acc += Z . Whi ----
#pragma unroll
    for (int k = 0; k < 8; ++k) {
      const int cb = k & 1, nb = cb ^ 1;
      if (k < 7) {
#pragma unroll
        for (int nt = 0; nt < 4; ++nt) Bf[nb][nt] = WREAD(0, nt, k + 1);
      } else {
        // wrap: next tg's LO k=0 (same every tg; W is t-stationary)
#pragma unroll
        for (int nt = 0; nt < 4; ++nt) Bf[nb][nt] = WREAD(1, nt, 0);
      }
#pragma unroll
      for (int j = 0; j < 4; ++j) {
        half8 Af = unpack_byte_f16((zb[j][k] >> q8) & 0xFFu);
#pragma unroll
        for (int nt = 0; nt < 4; ++nt)
          acc[j][nt] = __builtin_amdgcn_mfma_f32_16x16x32_f16(
              Af, Bf[cb][nt], acc[j][nt], 0, 0, 0);
      }
      __builtin_amdgcn_sched_barrier(0);
    }

    // ---- zb for next tg: issue now, ~1200 VALU cycles of LIF cover ----
    if (tg < TT / 4 - 1) {
#pragma unroll
      for (int j = 0; j < 4; ++j) {
        const uint32_t* p = zrow + ((size_t)(tg + 1) * 4 + j) * (size_t)(BB * 8);
        uint4 a = *(const uint4*)p;
        uint4 bq = *(const uint4*)(p + 4);
        zb[j][0] = a.x; zb[j][1] = a.y; zb[j][2] = a.z; zb[j][3] = a.w;
        zb[j][4] = bq.x; zb[j][5] = bq.y; zb[j][6] = bq.z; zb[j][7] = bq.w;
      }
    }

    // ---- 4 sequential layer-2 LIF updates (numpy op order) ----
#pragma unroll
    for (int j = 0; j < 4; ++j) {
#pragma unroll
      for (int nt = 0; nt < 4; ++nt) {
#pragma unroll
        for (int r = 0; r < 4; ++r) {
          float h  = __fadd_rn(acc[j][nt][r], bias[nt]);
          float vv = v2[nt][r], ci = ii[nt][r];
          float vd   = __fadd_rn(vv, __fmul_rn(K_VM, __fadd_rn(-vv, ci)));
          float idec = __fmul_rn(ci, K_ID);
          bool z = (vd > 1.0f);
          v2[nt][r] = z ? 0.0f : vd;
          ii[nt][r] = __fadd_rn(idec, h);
          sc[nt][r] = __fadd_rn(sc[nt][r], z ? 1.0f : 0.0f);
        }
      }
    }
  }
#undef WREAD

  // ---- epilogue: readout GEMM, fused ----
  float mean[4][4];
#pragma unroll
  for (int nt = 0; nt < 4; ++nt)
#pragma unroll
    for (int r = 0; r < 4; ++r) mean[nt][r] = __fdiv_rn(sc[nt][r], 100.0f);

#pragma unroll 1
  for (int c = 0; c < CC; ++c) {
    float wc[4];
#pragma unroll
    for (int nt = 0; nt < 4; ++nt) wc[nt] = Wr[c * HH + h0 + nt * 16 + col];
#pragma unroll
    for (int r = 0; r < 4; ++r) {
      float s = 0.f;
#pragma unroll
      for (int nt = 0; nt < 4; ++nt) s = fmaf(mean[nt][r], wc[nt], s);
      s += __shfl_xor(s, 1);
      s += __shfl_xor(s, 2);
      s += __shfl_xor(s, 4);
      s += __shfl_xor(s, 8);
      if (col == 0) {
        int b = b0 + wv * 16 + quad * 4 + r;
        float add = s + ((hc == 0) ? br[c] : 0.0f);
        atomicAdd(&out[b * CC + c], add);
      }
    }
  }
}

extern "C" void kernel_launch(void* const* d_in, const int* in_sizes, int n_in,
                              void* d_out, int out_size, void* d_ws, size_t ws_size,
                              hipStream_t stream) {
  const float* x  = (const float*)d_in[0];
  const float* Wh = (const float*)d_in[1];
  const float* bh = (const float*)d_in[2];
  const float* Wr = (const float*)d_in[3];
  const float* br = (const float*)d_in[4];
  float* out = (float*)d_out;

  // workspace: spike bitmask, 100*16384*32B = 52.4 MB
  unsigned long long* Z = (unsigned long long*)d_ws;

  hipMemsetAsync(d_out, 0, (size_t)out_size * sizeof(float), stream);
  spike_gen<<<BB / 16, 256, 0, stream>>>(x, Z);
  snn_main<<<(BB / 64) * 4, 256, 0, stream>>>((const uint32_t*)Z, Wh, bh, Wr, br, out);
}

// Round 5
// 433.946 us; speedup vs baseline: 1.6188x; 1.6188x over previous
//
#include <hip/hip_runtime.h>
#include <hip/hip_fp16.h>
#include <stdint.h>

// SNNClassifier: B=16384, F=256, H=256, C=10, T=100
// Phase 1: layer-1 LIF spike bitmask into d_ws (100 x 16384 x 256 bits).
// Phase 2: persistent-state fused kernel, R5 = int8 fused-digit GEMM:
//   W*2^14 = a*64 + b (a,b int8 digits); h = (sum a*(64 z) + b*z)*2^-14
//   via mfma_i32_16x16x64_i8 with A-operands {64z, z} - single exact i32
//   accumulator, one fp32 rounding at the end. 2x MAC rate vs f16 and
//   half the split-2 f16 MFMA count: floor 207us -> 109us.
// R2-R4 lesson: unrolled k-loops blow the register allocator (up to 1.25GB
// scratch traffic) while perf stays pinned at the f16 MFMA floor (~190us
// busy). R5 attacks the floor (i8) AND the pressure:
//   - W digits stored in MFMA-fragment order: lane-sequential 1024B blocks,
//     conflict-free ds_read_b128, ONE vgpr address + imm offsets, 32KB LDS.
//   - s-loop rolled (#pragma unroll 1): no 32-fragment hoisting possible.
//   - Z bits compacted at load to per-lane halfwords (16 regs, not 32).
//   - nibble unpack: (nib*0x204081)&0x01010101 -> 4 i8 0/1 bytes, <<6 for 64z.

#define BB 16384
#define FF 256
#define HH 256
#define CC 10
#define TT 100

typedef __attribute__((ext_vector_type(4))) int int4v;

// ---------------- kernel 1: layer-1 spike bitmask ----------------
// Block = 256 thr = 4 waves; wave owns 4 b-values x 4 segs (16 LIF states
// per thread). Per t, lanes 0..15 store 16 u64 = 128B contiguous.
__global__ __launch_bounds__(256) void spike_gen(
    const float* __restrict__ x, unsigned long long* __restrict__ Z) {
  const int lane = threadIdx.x & 63;
  const int wv   = threadIdx.x >> 6;
  const int b0   = blockIdx.x * 16 + wv * 4;  // this wave's 4 b-values
  const float K_VM = (float)(0.001 * 100.0);        // 0.1f, numpy-exact
  const float K_ID = (float)(1.0 - 0.001 * 200.0);  // 0.8f, numpy-exact

  float v[16], cur[16], xv[16];
#pragma unroll
  for (int jb = 0; jb < 4; ++jb)
#pragma unroll
    for (int js = 0; js < 4; ++js) {
      const int idx = jb * 4 + js;
      xv[idx] = x[(size_t)(b0 + jb) * FF + js * 64 + lane];
      v[idx] = 0.0f; cur[idx] = 0.0f;
    }

  unsigned long long mymask = 0;
  unsigned long long* zp = Z + (size_t)b0 * 4;  // row slot base (u64 units)

  for (int t = 0; t < TT; ++t) {
#pragma unroll
    for (int idx = 0; idx < 16; ++idx) {
      float vd   = __fadd_rn(v[idx], __fmul_rn(K_VM, __fadd_rn(-v[idx], cur[idx])));
      float idec = __fmul_rn(cur[idx], K_ID);
      bool z = (vd > 1.0f);
      unsigned long long m = __ballot(z);
      if (lane == idx) mymask = m;  // lane idx owns slot (b0+jb)*4+js
      v[idx]   = z ? 0.0f : vd;
      cur[idx] = __fadd_rn(idec, xv[idx]);
    }
    if (lane < 16) zp[(size_t)t * (BB * 4) + lane] = mymask;
  }
}

// ---------------- kernel 2: fused temporal loop (i8) ----------------
// grid: (B/64) b-chunks x 4 h-chunks. block=256 (4 waves).
// wave tile: 16 b-rows x 64 h-cols, 4 timestep-planes per group.
// LDS layout: 32 blocks of 1024B, block index (nt*2+d)*4+s, content byte
// [lane*16 + i] = digit d of W[h0w + nt*16 + (lane&15)]
//                              [s*64 + (lane>>4)*16 + i]   (i = 0..15)
__global__ __launch_bounds__(256, 2) void snn_main(
    const uint32_t* __restrict__ Z, const float* __restrict__ Wh,
    const float* __restrict__ bh, const float* __restrict__ Wr,
    const float* __restrict__ br, float* __restrict__ out) {
  __shared__ __align__(16) char WS[32768];

  const int tid = threadIdx.x;
  const int bx  = blockIdx.x;
  const int hc  = bx & 3;
  const int bc  = bx >> 2;
  const int h0  = hc * 64;
  const int b0  = bc * 64;

  // ---- stage W -> LDS as i8 digit pair (a = rint(W*256), b = residual),
  //      written directly in MFMA-fragment order ----
  {
    const int r = tid & 63;        // h-row 0..63
    const int w = tid >> 6;        // f-quarter = k-step s
    const int nt = r >> 4, n = r & 15;
    const float* wrow = Wh + (size_t)(h0 + r) * FF + w * 64;
    int4v* ws4 = (int4v*)WS;
#pragma unroll
    for (int q = 0; q < 4; ++q) {
      uint32_t pa[4], pb[4];
#pragma unroll
      for (int c4 = 0; c4 < 4; ++c4) {
        float4 w4 = *(const float4*)(wrow + q * 16 + c4 * 4);
        float wf[4] = {w4.x, w4.y, w4.z, w4.w};
        uint32_t ua = 0, ub = 0;
#pragma unroll
        for (int e = 0; e < 4; ++e) {
          float af = rintf(wf[e] * 256.0f);
          af = fminf(fmaxf(af, -127.0f), 127.0f);
          float bf = rintf(__builtin_fmaf(af, -64.0f, wf[e] * 16384.0f));
          int ai = (int)af, bi = (int)bf;
          ua |= ((uint32_t)ai & 255u) << (8 * e);
          ub |= ((uint32_t)bi & 255u) << (8 * e);
        }
        pa[c4] = ua; pb[c4] = ub;
      }
      ws4[((nt * 2 + 0) * 4 + w) * 64 + q * 16 + n] = *(int4v*)pa;
      ws4[((nt * 2 + 1) * 4 + w) * 64 + q * 16 + n] = *(int4v*)pb;
    }
  }
  __syncthreads();

  const int lane = tid & 63;
  const int wv   = tid >> 6;       // wave 0..3 -> b sub-tile
  const int col  = lane & 15;      // A: m-row / B: n-col / C: col
  const int quad = lane >> 4;
  const bool qhi = (quad & 2) != 0;      // which zb word pair
  const uint32_t shl16 = (quad & 1) * 16; // which halfword

  const int brow = b0 + wv * 16 + col;  // A-operand b row for this lane

  const float K_VM = (float)(0.001 * 100.0);
  const float K_ID = (float)(1.0 - 0.001 * 200.0);

  float v2[4][4], ii[4][4];
  uint32_t sc[4][4];
#pragma unroll
  for (int nt = 0; nt < 4; ++nt)
#pragma unroll
    for (int r = 0; r < 4; ++r) { v2[nt][r] = 0.f; ii[nt][r] = 0.f; sc[nt][r] = 0u; }

  float bias[4];
#pragma unroll
  for (int nt = 0; nt < 4; ++nt) bias[nt] = bh[h0 + nt * 16 + col];

  // per-lane compacted spike halfwords: hwS<s>[j] = 16 bits this lane needs
  // at k-step s, t-plane j (bits [s*64 + quad*16 .. +15] of Z row brow)
  uint32_t hwS0[4], hwS1[4], hwS2[4], hwS3[4];
  const uint32_t* zrow = Z + (size_t)brow * 8;

  auto load_hw = [&](int tgi) {
#pragma unroll
    for (int j = 0; j < 4; ++j) {
      const uint32_t* p = zrow + ((size_t)tgi * 4 + j) * (size_t)(BB * 8);
      uint4 a = *(const uint4*)p;
      uint4 b4 = *(const uint4*)(p + 4);
      hwS0[j] = (qhi ? a.y : a.x) >> shl16;
      hwS1[j] = (qhi ? a.w : a.z) >> shl16;
      hwS2[j] = (qhi ? b4.y : b4.x) >> shl16;
      hwS3[j] = (qhi ? b4.w : b4.z) >> shl16;
    }
  };
  load_hw(0);

  const char* wsl = WS + lane * 16;  // single runtime LDS base

#pragma unroll 1
  for (int tg = 0; tg < TT / 4; ++tg) {
    int4v acc[4][4];
#pragma unroll
    for (int j = 0; j < 4; ++j)
#pragma unroll
      for (int nt = 0; nt < 4; ++nt)
        acc[j][nt] = (int4v){0, 0, 0, 0};

    // ---- K loop: 4 steps of 64 f-columns, both digits fused ----
#pragma unroll 1
    for (int s = 0; s < 4; ++s) {
      const int4v* bp = (const int4v*)(wsl + s * 1024);
      int4v Ba[4], Bb[4];
#pragma unroll
      for (int nt = 0; nt < 4; ++nt) {
        Ba[nt] = bp[(nt * 2 + 0) * 256];  // imm offset (nt*2+0)*4096 B
        Bb[nt] = bp[(nt * 2 + 1) * 256];
      }
#pragma unroll
      for (int j = 0; j < 4; ++j) {
        uint32_t t0 = (s & 1) ? hwS1[j] : hwS0[j];
        uint32_t t1 = (s & 1) ? hwS3[j] : hwS2[j];
        uint32_t h16 = (s & 2) ? t1 : t0;
        int4v za, zb_;
#pragma unroll
        for (int p = 0; p < 4; ++p) {
          uint32_t nib = (h16 >> (4 * p)) & 15u;
          uint32_t zbyte = (nib * 0x204081u) & 0x01010101u;
          zb_[p] = (int)zbyte;
          za[p]  = (int)(zbyte << 6);  // 64*z, fits i8
        }
#pragma unroll
        for (int nt = 0; nt < 4; ++nt) {
          acc[j][nt] = __builtin_amdgcn_mfma_i32_16x16x64_i8(
              za, Ba[nt], acc[j][nt], 0, 0, 0);
          acc[j][nt] = __builtin_amdgcn_mfma_i32_16x16x64_i8(
              zb_, Bb[nt], acc[j][nt], 0, 0, 0);
        }
      }
    }

    // ---- prefetch next tg's spike bits (covered by LIF VALU) ----
    if (tg < TT / 4 - 1) load_hw(tg + 1);

    // ---- 4 sequential layer-2 LIF updates (numpy op order) ----
    // h = fl(acc*2^-14 + bias): cvt exact (|acc|<2^24), mul by 2^-14 exact.
#pragma unroll
    for (int j = 0; j < 4; ++j) {
#pragma unroll
      for (int nt = 0; nt < 4; ++nt) {
#pragma unroll
        for (int r = 0; r < 4; ++r) {
          float hq = __fmul_rn((float)acc[j][nt][r], 6.103515625e-05f);
          float h  = __fadd_rn(hq, bias[nt]);
          float vv = v2[nt][r], ci = ii[nt][r];
          float vd   = __fadd_rn(vv, __fmul_rn(K_VM, __fadd_rn(-vv, ci)));
          float idec = __fmul_rn(ci, K_ID);
          bool z = (vd > 1.0f);
          v2[nt][r] = z ? 0.0f : vd;
          ii[nt][r] = __fadd_rn(idec, h);
          sc[nt][r] += z ? 1u : 0u;
        }
      }
    }
  }

  // ---- epilogue: readout GEMM, fused ----
  // mean = (float)count / 100 : count exact in fp32, one div rounding (==np)
  float mean[4][4];
#pragma unroll
  for (int nt = 0; nt < 4; ++nt)
#pragma unroll
    for (int r = 0; r < 4; ++r) mean[nt][r] = __fdiv_rn((float)sc[nt][r], 100.0f);

#pragma unroll 1
  for (int c = 0; c < CC; ++c) {
    float wc[4];
#pragma unroll
    for (int nt = 0; nt < 4; ++nt) wc[nt] = Wr[c * HH + h0 + nt * 16 + col];
#pragma unroll
    for (int r = 0; r < 4; ++r) {
      float s = 0.f;
#pragma unroll
      for (int nt = 0; nt < 4; ++nt) s = fmaf(mean[nt][r], wc[nt], s);
      s += __shfl_xor(s, 1);
      s += __shfl_xor(s, 2);
      s += __shfl_xor(s, 4);
      s += __shfl_xor(s, 8);
      if (col == 0) {
        int b = b0 + wv * 16 + quad * 4 + r;
        float add = s + ((hc == 0) ? br[c] : 0.0f);
        atomicAdd(&out[b * CC + c], add);
      }
    }
  }
}

extern "C" void kernel_launch(void* const* d_in, const int* in_sizes, int n_in,
                              void* d_out, int out_size, void* d_ws, size_t ws_size,
                              hipStream_t stream) {
  const float* x  = (const float*)d_in[0];
  const float* Wh = (const float*)d_in[1];
  const float* bh = (const float*)d_in[2];
  const float* Wr = (const float*)d_in[3];
  const float* br = (const float*)d_in[4];
  float* out = (float*)d_out;

  // workspace: spike bitmask, 100*16384*32B = 52.4 MB
  unsigned long long* Z = (unsigned long long*)d_ws;

  hipMemsetAsync(d_out, 0, (size_t)out_size * sizeof(float), stream);
  spike_gen<<<BB / 16, 256, 0, stream>>>(x, Z);
  snn_main<<<(BB / 64) * 4, 256, 0, stream>>>((const uint32_t*)Z, Wh, bh, Wr, br, out);
}